// Round 5
// baseline (132.400 us; speedup 1.0000x reference)
//
#include <hip/hip_runtime.h>
#include <cstdint>
#include <cstddef>

// Problem constants
#define FF 64
#define EE 64
#define HH 8
#define PP 512
#define MM 16384   // B*T = 64*256
#define KK 1024    // 2 * F * H  (both branches concatenated)

typedef __bf16 bf16x8 __attribute__((ext_vector_type(8)));
typedef float  floatx4 __attribute__((ext_vector_type(4)));

// float -> bf16 (RNE)
__device__ __forceinline__ unsigned short f2bf(float f) {
    unsigned int u = __float_as_uint(f);
    u += 0x7FFFu + ((u >> 16) & 1u);
    return (unsigned short)(u >> 16);
}

__device__ __forceinline__ unsigned pack2(unsigned short a, unsigned short b) {
    return (unsigned)a | ((unsigned)b << 16);
}

// tanh from pre-scaled arg t = (val*w+b)*2*log2e:  1 - 2/(exp2(t)+1)
__device__ __forceinline__ float fast_tanh_s(float t) {
    float e, r;
    asm("v_exp_f32 %0, %1" : "=v"(e) : "v"(t));
    float d = e + 1.0f;
    asm("v_rcp_f32 %0, %1" : "=v"(r) : "v"(d));
    return __builtin_fmaf(-2.0f, r, 1.0f);
}

// async global->LDS, 16B per lane
__device__ __forceinline__ void gl_lds16(const unsigned short* g, unsigned short* s) {
    __builtin_amdgcn_global_load_lds(
        (__attribute__((address_space(1))) void*)(void*)g,
        (__attribute__((address_space(3))) void*)s,
        16, 0, 0);
}

// ---------------------------------------------------------------------------
// Phase 1: BmatT[n][k] (bf16, k-contiguous), k = br*512 + f*8 + h
//   BmatT[n][br,f,h] = sum_e w2[f,h,e] * W[(f*64+e)*512 + n]
// ---------------------------------------------------------------------------
__global__ __launch_bounds__(256) void combine_kernel(
    const float* __restrict__ w2v, const float* __restrict__ w2t,
    const float* __restrict__ wx,  const float* __restrict__ wt,
    unsigned short* __restrict__ BmatT)
{
    const int tid = threadIdx.x;
    const int bid = blockIdx.x;
    const int br = bid >> 7;
    const int f  = (bid >> 1) & 63;
    const int nh = bid & 1;
    const float* __restrict__ w2 = br ? w2t : w2v;   // [F][H][E]
    const float* __restrict__ W  = br ? wt  : wx;    // [F*E][P]
    __shared__ float w2s[HH * EE];
    for (int i = tid; i < HH * EE; i += 256) w2s[i] = w2[f * HH * EE + i];
    __syncthreads();
    const int n = nh * 256 + tid;
    float acc[HH] = {0,0,0,0,0,0,0,0};
    const float* Wcol = W + (size_t)f * EE * PP + n;
    #pragma unroll 8
    for (int e = 0; e < EE; ++e) {
        const float wv = Wcol[(size_t)e * PP];
        #pragma unroll
        for (int h = 0; h < HH; ++h)
            acc[h] = __builtin_fmaf(w2s[h * EE + e], wv, acc[h]);
    }
    uint4 v;
    v.x = pack2(f2bf(acc[0]), f2bf(acc[1]));
    v.y = pack2(f2bf(acc[2]), f2bf(acc[3]));
    v.z = pack2(f2bf(acc[4]), f2bf(acc[5]));
    v.w = pack2(f2bf(acc[6]), f2bf(acc[7]));
    *reinterpret_cast<uint4*>(&BmatT[(size_t)n * KK + br * 512 + f * 8]) = v;
}

// ---------------------------------------------------------------------------
// Phase 2: fused featurize + GEMM, software-pipelined tanh.
//   out[m][n] = sum_k A[m][k]*BmatT[n][k] + bx[n] + bt[n]
//   A[m][br*512+f*8+h] = tanh(in_br[m][f]*w1[f][h]+b1[f][h])  in-tile.
// 512 threads (8 waves), tile 64m x 256n, BK=64, grid (256 m-tiles, 2 n-tiles)
// -> tanh redundancy 2x, 2 blocks/CU (48 KB LDS), 4 waves/SIMD.
// Pipelining: thread's input vals (16 floats) prefetched to registers before
// the k-loop; the 8-tanh chunk for iter i+1 is computed in REGISTERS during
// iter i's MFMA phase (transcendental VALU interleaves with MFMA, separate
// pipes). The serial staging phase shrinks to: Bs DMA issue + one uint4 LDS
// store + barrier.
// XOR-swizzle (chunk c at physical c^(row&7)) on As and Bs; epilogue writes
// 4x64B contiguous per row.
// ---------------------------------------------------------------------------
__global__ __launch_bounds__(512, 4) void gemm_fused_kernel(
    const float* __restrict__ x,   const float* __restrict__ tmv,
    const float* __restrict__ w1v, const float* __restrict__ b1v,
    const float* __restrict__ w1t, const float* __restrict__ b1t,
    const unsigned short* __restrict__ Bt,  // BmatT [PP][KK]
    const float* __restrict__ bx, const float* __restrict__ bt,
    float* __restrict__ out)                 // [MM][PP]
{
    __shared__ __align__(16) unsigned short As[64 * 64];    // 8 KB
    __shared__ __align__(16) unsigned short Bs[256 * 64];   // 32 KB
    __shared__ __align__(16) float w1s[2 * FF * HH];        // 4 KB (pre-scaled)
    __shared__ __align__(16) float b1s[2 * FF * HH];        // 4 KB (pre-scaled)

    const int tid  = threadIdx.x;
    const int wave = tid >> 6;
    const int lane = tid & 63;
    const int m0 = blockIdx.x * 64;
    const int n0 = blockIdx.y * 256;

    // stage w1/b1 scaled by 2*log2e
    {
        const float c = 2.8853900817779268f;
        #pragma unroll
        for (int t = 0; t < 2; ++t) {
            const int idx = tid + t * 512;
            const int br  = idx >> 9;
            const int rem = idx & 511;
            w1s[idx] = (br ? w1t : w1v)[rem] * c;
            b1s[idx] = (br ? b1t : b1v)[rem] * c;
        }
    }

    const int wm  = wave >> 2;             // 0..1  (m quadrant, 32 rows)
    const int wn  = wave & 3;              // 0..3  (n quadrant, 64 cols)
    const int q   = lane >> 4;
    const int ml  = lane & 15;
    const int mlx = ml & 7;
    const int lr  = lane >> 3;             // 0..7 row within 8-row segment
    const int lkg = ((lane & 7) ^ lr) * 8; // swizzled global k-offset (shorts)
    const int fi  = tid & 7;               // feature sub-index for A-compute
    const int arow = tid >> 3;             // 0..63: A row this thread computes
    const int pchunk = (fi ^ (arow & 7)) * 8;

    // prefetch this thread's 16 input values (8 f-slices per branch)
    float xv[8], tv[8];
    {
        const float* xrow = x   + (size_t)(m0 + arow) * FF + fi;
        const float* trow = tmv + (size_t)(m0 + arow) * FF + fi;
        #pragma unroll
        for (int j = 0; j < 8; ++j) { xv[j] = xrow[8 * j]; tv[j] = trow[8 * j]; }
    }
    __syncthreads();   // w1s/b1s ready

    // tanh chunk for iteration `it` (k0 = it*64): br = it>>3, f = (it&7)*8+fi
    auto tanh_chunk = [&](int it) -> uint4 {
        const int br = it >> 3;
        const int j  = it & 7;
        const int f  = j * 8 + fi;
        const float val = br ? tv[j] : xv[j];
        const float4 wlo = reinterpret_cast<const float4*>(w1s)[br * 128 + f * 2];
        const float4 whi = reinterpret_cast<const float4*>(w1s)[br * 128 + f * 2 + 1];
        const float4 blo = reinterpret_cast<const float4*>(b1s)[br * 128 + f * 2];
        const float4 bhi = reinterpret_cast<const float4*>(b1s)[br * 128 + f * 2 + 1];
        float hv[8];
        hv[0] = fast_tanh_s(__builtin_fmaf(val, wlo.x, blo.x));
        hv[1] = fast_tanh_s(__builtin_fmaf(val, wlo.y, blo.y));
        hv[2] = fast_tanh_s(__builtin_fmaf(val, wlo.z, blo.z));
        hv[3] = fast_tanh_s(__builtin_fmaf(val, wlo.w, blo.w));
        hv[4] = fast_tanh_s(__builtin_fmaf(val, whi.x, bhi.x));
        hv[5] = fast_tanh_s(__builtin_fmaf(val, whi.y, bhi.y));
        hv[6] = fast_tanh_s(__builtin_fmaf(val, whi.z, bhi.z));
        hv[7] = fast_tanh_s(__builtin_fmaf(val, whi.w, bhi.w));
        uint4 v;
        v.x = pack2(f2bf(hv[0]), f2bf(hv[1]));
        v.y = pack2(f2bf(hv[2]), f2bf(hv[3]));
        v.z = pack2(f2bf(hv[4]), f2bf(hv[5]));
        v.w = pack2(f2bf(hv[6]), f2bf(hv[7]));
        return v;
    };

    floatx4 acc[2][4];
    #pragma unroll
    for (int i = 0; i < 2; ++i)
        #pragma unroll
        for (int j = 0; j < 4; ++j)
            acc[i][j] = (floatx4){0.f, 0.f, 0.f, 0.f};

    uint4 v = tanh_chunk(0);

    for (int it = 0; it < 16; ++it) {
        const int k0 = it * 64;

        // ---- staging phase (short): Bs DMA + one As store ----
        #pragma unroll
        for (int i = 0; i < 4; ++i) {
            const int seg = wave * 4 + i;        // 0..31
            gl_lds16(&Bt[(size_t)(n0 + seg * 8 + lr) * KK + k0 + lkg], &Bs[seg * 512]);
        }
        *reinterpret_cast<uint4*>(&As[arow * 64 + pchunk]) = v;
        __syncthreads();   // As stores + Bs DMA visible

        // ---- next iteration's tanh (registers) — overlaps MFMA below ----
        uint4 vn = v;
        if (it < 15) vn = tanh_chunk(it + 1);

        // ---- MFMA phase ----
        #pragma unroll
        for (int kk = 0; kk < 64; kk += 32) {
            const int cl = (kk >> 3) + q;          // logical chunk 0..7
            const int co = (cl ^ mlx) * 8;          // swizzled offset (shorts)
            bf16x8 af[2], bfr[4];
            #pragma unroll
            for (int mt = 0; mt < 2; ++mt)
                af[mt] = *reinterpret_cast<const bf16x8*>(
                    &As[(wm * 32 + mt * 16 + ml) * 64 + co]);
            #pragma unroll
            for (int nt = 0; nt < 4; ++nt)
                bfr[nt] = *reinterpret_cast<const bf16x8*>(
                    &Bs[(wn * 64 + nt * 16 + ml) * 64 + co]);
            #pragma unroll
            for (int mt = 0; mt < 2; ++mt)
                #pragma unroll
                for (int nt = 0; nt < 4; ++nt)
                    acc[mt][nt] = __builtin_amdgcn_mfma_f32_16x16x32_bf16(
                        af[mt], bfr[nt], acc[mt][nt], 0, 0, 0);
        }
        __syncthreads();   // before next iteration overwrites LDS
        v = vn;
    }

    // epilogue: nt innermost -> 4 consecutive 64B chunks per output row
    float bias[4];
    #pragma unroll
    for (int nt = 0; nt < 4; ++nt) {
        const int n = n0 + wn * 64 + nt * 16 + ml;
        bias[nt] = bx[n] + bt[n];
    }
    #pragma unroll
    for (int mt = 0; mt < 2; ++mt) {
        const int mb = m0 + wm * 32 + mt * 16 + q * 4;
        #pragma unroll
        for (int r = 0; r < 4; ++r) {
            float* orow = out + (size_t)(mb + r) * PP + n0 + wn * 64 + ml;
            #pragma unroll
            for (int nt = 0; nt < 4; ++nt)
                orow[nt * 16] = acc[mt][nt][r] + bias[nt];
        }
    }
}

// ---------------------------------------------------------------------------
extern "C" void kernel_launch(void* const* d_in, const int* in_sizes, int n_in,
                              void* d_out, int out_size, void* d_ws, size_t ws_size,
                              hipStream_t stream)
{
    const float* x   = (const float*)d_in[0];
    const float* tmv = (const float*)d_in[1];
    const float* w1v = (const float*)d_in[2];
    const float* b1v = (const float*)d_in[3];
    const float* w2v = (const float*)d_in[4];
    const float* w1t = (const float*)d_in[5];
    const float* b1t = (const float*)d_in[6];
    const float* w2t = (const float*)d_in[7];
    const float* wx  = (const float*)d_in[8];
    const float* bx  = (const float*)d_in[9];
    const float* wt  = (const float*)d_in[10];
    const float* bt  = (const float*)d_in[11];
    float* out = (float*)d_out;

    // ws: [0,1MB) BmatT bf16 [512][1024]
    unsigned short* Bws = (unsigned short*)d_ws;

    combine_kernel<<<256, 256, 0, stream>>>(w2v, w2t, wx, wt, Bws);
    gemm_fused_kernel<<<dim3(MM / 64, PP / 256), 512, 0, stream>>>(
        x, tmv, w1v, b1v, w1t, b1t, Bws, bx, bt, out);
}

// Round 6
// 126.470 us; speedup vs baseline: 1.0469x; 1.0469x over previous
//
#include <hip/hip_runtime.h>
#include <cstdint>
#include <cstddef>

// Problem constants
#define FF 64
#define EE 64
#define HH 8
#define PP 512
#define MM 16384   // B*T = 64*256
#define KK 1024    // 2 * F * H  (both branches concatenated)

typedef __bf16 bf16x8 __attribute__((ext_vector_type(8)));
typedef float  floatx4 __attribute__((ext_vector_type(4)));

// float -> bf16 (RNE)
__device__ __forceinline__ unsigned short f2bf(float f) {
    unsigned int u = __float_as_uint(f);
    u += 0x7FFFu + ((u >> 16) & 1u);
    return (unsigned short)(u >> 16);
}

__device__ __forceinline__ unsigned pack2(unsigned short a, unsigned short b) {
    return (unsigned)a | ((unsigned)b << 16);
}

// tanh from pre-scaled arg t = (val*w+b)*2*log2e:  1 - 2/(exp2(t)+1)
__device__ __forceinline__ float fast_tanh_s(float t) {
    float e, r;
    asm("v_exp_f32 %0, %1" : "=v"(e) : "v"(t));
    float d = e + 1.0f;
    asm("v_rcp_f32 %0, %1" : "=v"(r) : "v"(d));
    return __builtin_fmaf(-2.0f, r, 1.0f);
}

// async global->LDS, 16B per lane
__device__ __forceinline__ void gl_lds16(const unsigned short* g, unsigned short* s) {
    __builtin_amdgcn_global_load_lds(
        (__attribute__((address_space(1))) void*)(void*)g,
        (__attribute__((address_space(3))) void*)s,
        16, 0, 0);
}

// ---------------------------------------------------------------------------
// Phase 1: BmatT[n][k] (bf16, k-contiguous), k = br*512 + f*8 + h
//   BmatT[n][br,f,h] = sum_e w2[f,h,e] * W[(f*64+e)*512 + n]
// ---------------------------------------------------------------------------
__global__ __launch_bounds__(256) void combine_kernel(
    const float* __restrict__ w2v, const float* __restrict__ w2t,
    const float* __restrict__ wx,  const float* __restrict__ wt,
    unsigned short* __restrict__ BmatT)
{
    const int tid = threadIdx.x;
    const int bid = blockIdx.x;
    const int br = bid >> 7;
    const int f  = (bid >> 1) & 63;
    const int nh = bid & 1;
    const float* __restrict__ w2 = br ? w2t : w2v;   // [F][H][E]
    const float* __restrict__ W  = br ? wt  : wx;    // [F*E][P]
    __shared__ float w2s[HH * EE];
    for (int i = tid; i < HH * EE; i += 256) w2s[i] = w2[f * HH * EE + i];
    __syncthreads();
    const int n = nh * 256 + tid;
    float acc[HH] = {0,0,0,0,0,0,0,0};
    const float* Wcol = W + (size_t)f * EE * PP + n;
    #pragma unroll 8
    for (int e = 0; e < EE; ++e) {
        const float wv = Wcol[(size_t)e * PP];
        #pragma unroll
        for (int h = 0; h < HH; ++h)
            acc[h] = __builtin_fmaf(w2s[h * EE + e], wv, acc[h]);
    }
    uint4 v;
    v.x = pack2(f2bf(acc[0]), f2bf(acc[1]));
    v.y = pack2(f2bf(acc[2]), f2bf(acc[3]));
    v.z = pack2(f2bf(acc[4]), f2bf(acc[5]));
    v.w = pack2(f2bf(acc[6]), f2bf(acc[7]));
    *reinterpret_cast<uint4*>(&BmatT[(size_t)n * KK + br * 512 + f * 8]) = v;
}

// ---------------------------------------------------------------------------
// Phase 2: fused featurize + GEMM.
//   out[m][n] = sum_k A[m][k]*BmatT[n][k] + bx[n] + bt[n]
//   A[m][br*512+f*8+h] = tanh(in_br[m][f]*w1[f][h]+b1[f][h])  in-tile.
// 256 threads / 4 waves, each wave a FULL 64x64 tile (4x4 acc of 16x16x32)
// -> fragment LDS traffic (Wm+Wn)/(Wm*Wn) = 1/32 B/FLOP = 537 MB total,
//    at parity with the ~7us MFMA floor (r4/r5's 32x64 waves were LDS-bound).
// Block tile 64m x 256n (waves = 1m x 4n), BK=64, grid (256,2) = 512 blocks
// -> 2 blocks/CU (LDS 48 KB, cap 3) for cross-block barrier overlap,
//    tanh redundancy 2x.
// Pipeline: iter it+1's inputs (2 global floats) + w/b (4 LDS float4) load in
// the STAGING phase (drained by the existing barrier, zero extra waits); the
// 16 tanh for it+1 run in the MFMA phase as PURE VALU (no lgkm pollution —
// r5's mistake). Results stored to As at the top of it+1.
// XOR-swizzle: row r's logical 16B chunk c at physical c^(r&7), both tiles.
// ---------------------------------------------------------------------------
__global__ __launch_bounds__(256, 3) void gemm_fused_kernel(
    const float* __restrict__ x,   const float* __restrict__ tmv,
    const float* __restrict__ w1v, const float* __restrict__ b1v,
    const float* __restrict__ w1t, const float* __restrict__ b1t,
    const unsigned short* __restrict__ Bt,  // BmatT [PP][KK]
    const float* __restrict__ bx, const float* __restrict__ bt,
    float* __restrict__ out)                 // [MM][PP]
{
    __shared__ __align__(16) unsigned short As[64 * 64];    // 8 KB
    __shared__ __align__(16) unsigned short Bs[256 * 64];   // 32 KB
    __shared__ __align__(16) float w1s[2 * FF * HH];        // 4 KB (pre-scaled)
    __shared__ __align__(16) float b1s[2 * FF * HH];        // 4 KB (pre-scaled)

    const int tid  = threadIdx.x;
    const int wave = tid >> 6;
    const int lane = tid & 63;
    const int m0 = blockIdx.x * 64;
    const int n0 = blockIdx.y * 256;

    // stage w1/b1 scaled by 2*log2e: one w-float4 + one b-float4 per thread
    {
        const float c = 2.8853900817779268f;
        const float4 wsrc = (tid < 128) ? reinterpret_cast<const float4*>(w1v)[tid]
                                        : reinterpret_cast<const float4*>(w1t)[tid - 128];
        const float4 bsrc = (tid < 128) ? reinterpret_cast<const float4*>(b1v)[tid]
                                        : reinterpret_cast<const float4*>(b1t)[tid - 128];
        float4 ws, bs;
        ws.x = wsrc.x * c; ws.y = wsrc.y * c; ws.z = wsrc.z * c; ws.w = wsrc.w * c;
        bs.x = bsrc.x * c; bs.y = bsrc.y * c; bs.z = bsrc.z * c; bs.w = bsrc.w * c;
        reinterpret_cast<float4*>(w1s)[tid] = ws;
        reinterpret_cast<float4*>(b1s)[tid] = bs;
    }

    const int wn  = wave;                  // 0..3: n quadrant (64 cols each)
    const int q   = lane >> 4;
    const int ml  = lane & 15;
    const int mlx = ml & 7;
    const int lr  = lane >> 3;             // 0..7 row within 8-row segment
    const int lkg = ((lane & 7) ^ lr) * 8; // swizzled global k-offset (shorts)
    const int fi  = tid & 7;               // feature sub-index for A-compute
    const int g   = tid >> 3;              // 0..31: A rows g and g+32
    const int pchunkA = (fi ^ (g & 7)) * 8;  // same for row g+32 ((g+32)&7==g&7)

    __syncthreads();   // w1s/b1s ready

    // pipeline registers: weights/bias + input vals + packed tanh results
    float4 wlo, whi, blo, bhi;
    float  va, vb;
    uint4  pa, pb;

    // prologue: load + compute chunk for it=0 (br=0, f=fi)
    {
        wlo = reinterpret_cast<const float4*>(w1s)[fi * 2];
        whi = reinterpret_cast<const float4*>(w1s)[fi * 2 + 1];
        blo = reinterpret_cast<const float4*>(b1s)[fi * 2];
        bhi = reinterpret_cast<const float4*>(b1s)[fi * 2 + 1];
        va = x[(size_t)(m0 + g) * FF + fi];
        vb = x[(size_t)(m0 + g + 32) * FF + fi];
    }

    auto tanh_pack = [&](float val) -> uint4 {
        float hv[8];
        hv[0] = fast_tanh_s(__builtin_fmaf(val, wlo.x, blo.x));
        hv[1] = fast_tanh_s(__builtin_fmaf(val, wlo.y, blo.y));
        hv[2] = fast_tanh_s(__builtin_fmaf(val, wlo.z, blo.z));
        hv[3] = fast_tanh_s(__builtin_fmaf(val, wlo.w, blo.w));
        hv[4] = fast_tanh_s(__builtin_fmaf(val, whi.x, bhi.x));
        hv[5] = fast_tanh_s(__builtin_fmaf(val, whi.y, bhi.y));
        hv[6] = fast_tanh_s(__builtin_fmaf(val, whi.z, bhi.z));
        hv[7] = fast_tanh_s(__builtin_fmaf(val, whi.w, bhi.w));
        uint4 v;
        v.x = pack2(f2bf(hv[0]), f2bf(hv[1]));
        v.y = pack2(f2bf(hv[2]), f2bf(hv[3]));
        v.z = pack2(f2bf(hv[4]), f2bf(hv[5]));
        v.w = pack2(f2bf(hv[6]), f2bf(hv[7]));
        return v;
    };
    pa = tanh_pack(va);
    pb = tanh_pack(vb);

    floatx4 acc[4][4];
    #pragma unroll
    for (int i = 0; i < 4; ++i)
        #pragma unroll
        for (int j = 0; j < 4; ++j)
            acc[i][j] = (floatx4){0.f, 0.f, 0.f, 0.f};

    for (int it = 0; it < 16; ++it) {
        const int k0 = it * 64;

        // ---- staging phase ----
        #pragma unroll
        for (int i = 0; i < 8; ++i) {
            const int seg = wave * 8 + i;        // 0..31
            gl_lds16(&Bt[(size_t)(n0 + seg * 8 + lr) * KK + k0 + lkg], &Bs[seg * 512]);
        }
        *reinterpret_cast<uint4*>(&As[g * 64 + pchunkA])        = pa;
        *reinterpret_cast<uint4*>(&As[(g + 32) * 64 + pchunkA]) = pb;

        // prefetch it+1's inputs + weights (counters drain at the barrier,
        // which exists anyway -> zero added wait)
        const int itn = (it < 15) ? it + 1 : 15;
        const int brn = itn >> 3;
        const int fn  = ((itn & 7) << 3) + fi;
        const float* __restrict__ inpn = brn ? tmv : x;
        const float nva = inpn[(size_t)(m0 + g) * FF + fn];
        const float nvb = inpn[(size_t)(m0 + g + 32) * FF + fn];
        const float4 nwlo = reinterpret_cast<const float4*>(w1s)[brn * 128 + fn * 2];
        const float4 nwhi = reinterpret_cast<const float4*>(w1s)[brn * 128 + fn * 2 + 1];
        const float4 nblo = reinterpret_cast<const float4*>(b1s)[brn * 128 + fn * 2];
        const float4 nbhi = reinterpret_cast<const float4*>(b1s)[brn * 128 + fn * 2 + 1];

        __syncthreads();   // As stores + Bs DMA visible; prefetches complete

        wlo = nwlo; whi = nwhi; blo = nblo; bhi = nbhi;
        va = nva; vb = nvb;

        // ---- MFMA phase (tanh for it+1 interleaved as pure VALU) ----
        {
            const int co0 = ((0 + q) ^ mlx) * 8;    // kk=0 swizzled offset
            bf16x8 af[4], bfr[4];
            #pragma unroll
            for (int mt = 0; mt < 4; ++mt)
                af[mt] = *reinterpret_cast<const bf16x8*>(&As[(mt * 16 + ml) * 64 + co0]);
            #pragma unroll
            for (int nt = 0; nt < 4; ++nt)
                bfr[nt] = *reinterpret_cast<const bf16x8*>(
                    &Bs[(wn * 64 + nt * 16 + ml) * 64 + co0]);
            #pragma unroll
            for (int mt = 0; mt < 4; ++mt)
                #pragma unroll
                for (int nt = 0; nt < 4; ++nt)
                    acc[mt][nt] = __builtin_amdgcn_mfma_f32_16x16x32_bf16(
                        af[mt], bfr[nt], acc[mt][nt], 0, 0, 0);

            // next-iter tanh: no memory ops -> overlaps MFMA issue
            pa = tanh_pack(va);
            pb = tanh_pack(vb);

            const int co1 = ((4 + q) ^ mlx) * 8;    // kk=32 swizzled offset
            #pragma unroll
            for (int mt = 0; mt < 4; ++mt)
                af[mt] = *reinterpret_cast<const bf16x8*>(&As[(mt * 16 + ml) * 64 + co1]);
            #pragma unroll
            for (int nt = 0; nt < 4; ++nt)
                bfr[nt] = *reinterpret_cast<const bf16x8*>(
                    &Bs[(wn * 64 + nt * 16 + ml) * 64 + co1]);
            #pragma unroll
            for (int mt = 0; mt < 4; ++mt)
                #pragma unroll
                for (int nt = 0; nt < 4; ++nt)
                    acc[mt][nt] = __builtin_amdgcn_mfma_f32_16x16x32_bf16(
                        af[mt], bfr[nt], acc[mt][nt], 0, 0, 0);
        }
        __syncthreads();   // before next iteration overwrites LDS
    }

    // epilogue: nt innermost -> 4 consecutive 64B chunks per output row
    float bias[4];
    #pragma unroll
    for (int nt = 0; nt < 4; ++nt) {
        const int n = n0 + wn * 64 + nt * 16 + ml;
        bias[nt] = bx[n] + bt[n];
    }
    #pragma unroll
    for (int mt = 0; mt < 4; ++mt) {
        const int mb = m0 + mt * 16 + q * 4;
        #pragma unroll
        for (int r = 0; r < 4; ++r) {
            float* orow = out + (size_t)(mb + r) * PP + n0 + wn * 64 + ml;
            #pragma unroll
            for (int nt = 0; nt < 4; ++nt)
                orow[nt * 16] = acc[mt][nt][r] + bias[nt];
        }
    }
}

// ---------------------------------------------------------------------------
extern "C" void kernel_launch(void* const* d_in, const int* in_sizes, int n_in,
                              void* d_out, int out_size, void* d_ws, size_t ws_size,
                              hipStream_t stream)
{
    const float* x   = (const float*)d_in[0];
    const float* tmv = (const float*)d_in[1];
    const float* w1v = (const float*)d_in[2];
    const float* b1v = (const float*)d_in[3];
    const float* w2v = (const float*)d_in[4];
    const float* w1t = (const float*)d_in[5];
    const float* b1t = (const float*)d_in[6];
    const float* w2t = (const float*)d_in[7];
    const float* wx  = (const float*)d_in[8];
    const float* bx  = (const float*)d_in[9];
    const float* wt  = (const float*)d_in[10];
    const float* bt  = (const float*)d_in[11];
    float* out = (float*)d_out;

    // ws: [0,1MB) BmatT bf16 [512][1024]
    unsigned short* Bws = (unsigned short*)d_ws;

    combine_kernel<<<256, 256, 0, stream>>>(w2v, w2t, wx, wt, Bws);
    gemm_fused_kernel<<<dim3(MM / 64, PP / 256), 256, 0, stream>>>(
        x, tmv, w1v, b1v, w1t, b1t, Bws, bx, bt, out);
}